// Round 1
// baseline (433.695 us; speedup 1.0000x reference)
//
#include <hip/hip_runtime.h>
#include <hip/hip_bf16.h>

// AdaptiveGraph: Z = X W^T (fp32, cast to bf16 for MFMA);
// A = rownorm(relu(Z Z^T)) [written fp32]; out = A Z.
// K1: Z + bf16 copies (Zb [n][h], ZbT [h][n]) into ws.
// K2: rowsum[n] = sum_m relu(Z_n . Z_m)  (bf16 MFMA, atomic partial sums)
// K3: recompute S tiles, A = relu(S)*inv_rowsum -> global fp32 + LDS bf16,
//     out += A_tile @ Z_tile (second MFMA), atomicAdd into d_out.

#define NROWS 8192
#define KDIM 256
#define HID 128

typedef short v8s __attribute__((ext_vector_type(8)));
typedef float v4f __attribute__((ext_vector_type(4)));

static __device__ __forceinline__ ushort f2bf(float f) {
    union { float f; unsigned u; } cv; cv.f = f;
    unsigned u = cv.u;
    u += 0x7fffu + ((u >> 16) & 1u);   // RNE; inputs are finite, no NaN handling needed
    return (ushort)(u >> 16);
}

// ---------------- K1: Z = X @ W^T ----------------
// grid 512, block 256. Each block: 16 rows of X. tid%128 = h, tid/128 picks 8 n's.
__global__ __launch_bounds__(256) void k_z(const float* __restrict__ X,
                                           const float* __restrict__ W,
                                           ushort* __restrict__ Zb,
                                           ushort* __restrict__ ZbT) {
    __shared__ float Xs[16][260];  // +4 pad
    int tid = threadIdx.x;
    int row0 = blockIdx.x * 16;
    for (int idx = tid; idx < 1024; idx += 256) {          // 16*256/4 float4 chunks
        int r = idx >> 6, c4 = (idx & 63) << 2;
        *(float4*)&Xs[r][c4] = *(const float4*)(X + (row0 + r) * KDIM + c4);
    }
    __syncthreads();
    int h = tid & 127, g = tid >> 7;
    float acc[8];
#pragma unroll
    for (int j = 0; j < 8; ++j) acc[j] = 0.f;
    for (int k = 0; k < KDIM; k += 4) {
        float4 w = *(const float4*)(W + h * KDIM + k);
#pragma unroll
        for (int j = 0; j < 8; ++j) {
            float4 x = *(const float4*)&Xs[g * 8 + j][k];  // broadcast across lanes
            acc[j] = fmaf(w.x, x.x, acc[j]);
            acc[j] = fmaf(w.y, x.y, acc[j]);
            acc[j] = fmaf(w.z, x.z, acc[j]);
            acc[j] = fmaf(w.w, x.w, acc[j]);
        }
    }
#pragma unroll
    for (int j = 0; j < 8; ++j) {
        int n = row0 + g * 8 + j;
        ushort z = f2bf(acc[j]);
        Zb[n * HID + h] = z;
        ZbT[h * NROWS + n] = z;
    }
}

// ---------------- K2: rowsum ----------------
// grid 512 = 128 row-blocks x 4 col-splits; block 256 (4 waves, each a 32x32 quadrant).
__global__ __launch_bounds__(256) void k_rowsum(const ushort* __restrict__ Zb,
                                                float* __restrict__ rowsum) {
    __shared__ ushort ZR[64][136];  // +8 pad: quarter-wave b128 reads -> 2-way (free)
    __shared__ ushort ZC[64][136];
    int tid = threadIdx.x;
    int rb = blockIdx.x >> 2, cs = blockIdx.x & 3;
    int row0 = rb * 64, colb = cs * 2048;
    for (int idx = tid; idx < 1024; idx += 256) {
        int r = idx >> 4, c8 = (idx & 15) << 3;
        *(uint4*)&ZR[r][c8] = *(const uint4*)(Zb + (row0 + r) * HID + c8);
    }
    int lane = tid & 63, wave = tid >> 6;
    int wr = wave >> 1, wc = wave & 1;
    int lq = lane >> 4, lm = lane & 15;
    float rs[2][4];
#pragma unroll
    for (int mi = 0; mi < 2; ++mi)
#pragma unroll
        for (int j = 0; j < 4; ++j) rs[mi][j] = 0.f;

    for (int it = 0; it < 32; ++it) {
        int c0 = colb + it * 64;
        __syncthreads();
        for (int idx = tid; idx < 1024; idx += 256) {
            int r = idx >> 4, c8 = (idx & 15) << 3;
            *(uint4*)&ZC[r][c8] = *(const uint4*)(Zb + (c0 + r) * HID + c8);
        }
        __syncthreads();
        v4f S00 = {0.f,0.f,0.f,0.f}, S01 = {0.f,0.f,0.f,0.f};
        v4f S10 = {0.f,0.f,0.f,0.f}, S11 = {0.f,0.f,0.f,0.f};
#pragma unroll
        for (int ks = 0; ks < 4; ++ks) {
            v8s a0 = *(const v8s*)&ZR[wr * 32 + lm][ks * 32 + lq * 8];
            v8s a1 = *(const v8s*)&ZR[wr * 32 + 16 + lm][ks * 32 + lq * 8];
            v8s b0 = *(const v8s*)&ZC[wc * 32 + lm][ks * 32 + lq * 8];
            v8s b1 = *(const v8s*)&ZC[wc * 32 + 16 + lm][ks * 32 + lq * 8];
            S00 = __builtin_amdgcn_mfma_f32_16x16x32_bf16(a0, b0, S00, 0, 0, 0);
            S01 = __builtin_amdgcn_mfma_f32_16x16x32_bf16(a0, b1, S01, 0, 0, 0);
            S10 = __builtin_amdgcn_mfma_f32_16x16x32_bf16(a1, b0, S10, 0, 0, 0);
            S11 = __builtin_amdgcn_mfma_f32_16x16x32_bf16(a1, b1, S11, 0, 0, 0);
        }
#pragma unroll
        for (int j = 0; j < 4; ++j) {
            rs[0][j] += fmaxf(S00[j], 0.f) + fmaxf(S01[j], 0.f);
            rs[1][j] += fmaxf(S10[j], 0.f) + fmaxf(S11[j], 0.f);
        }
    }
#pragma unroll
    for (int m = 1; m < 16; m <<= 1)
#pragma unroll
        for (int mi = 0; mi < 2; ++mi)
#pragma unroll
            for (int j = 0; j < 4; ++j)
                rs[mi][j] += __shfl_xor(rs[mi][j], m, 64);
    if (lm == 0) {
#pragma unroll
        for (int mi = 0; mi < 2; ++mi)
#pragma unroll
            for (int j = 0; j < 4; ++j)
                atomicAdd(&rowsum[row0 + wr * 32 + mi * 16 + lq * 4 + j], rs[mi][j]);
    }
}

// ---------------- K3: A write + out accumulate ----------------
__global__ __launch_bounds__(256) void k_main(const ushort* __restrict__ Zb,
                                              const ushort* __restrict__ ZbT,
                                              const float* __restrict__ rowsum,
                                              float* __restrict__ outp,
                                              float* __restrict__ Ap) {
    __shared__ ushort ZR[64][136];
    __shared__ ushort ZC[64][136];
    __shared__ ushort ZCT[128][72];  // Z tile transposed [h][c] for MFMA2 B-operand
    __shared__ ushort Abf[64][72];   // A tile bf16, C-layout -> A-operand layout via LDS
    __shared__ float rsinv[64];
    int tid = threadIdx.x;
    int rb = blockIdx.x >> 2, cs = blockIdx.x & 3;
    int row0 = rb * 64, colb = cs * 2048;
    for (int idx = tid; idx < 1024; idx += 256) {
        int r = idx >> 4, c8 = (idx & 15) << 3;
        *(uint4*)&ZR[r][c8] = *(const uint4*)(Zb + (row0 + r) * HID + c8);
    }
    if (tid < 64) rsinv[tid] = 1.0f / (rowsum[row0 + tid] + 1e-6f);
    __syncthreads();
    int lane = tid & 63, wave = tid >> 6;
    int wr = wave >> 1, wc = wave & 1;
    int lq = lane >> 4, lm = lane & 15;
    float rsv[2][4];
#pragma unroll
    for (int mi = 0; mi < 2; ++mi)
#pragma unroll
        for (int j = 0; j < 4; ++j)
            rsv[mi][j] = rsinv[wr * 32 + mi * 16 + lq * 4 + j];
    v4f O[2][4];
#pragma unroll
    for (int mi = 0; mi < 2; ++mi)
#pragma unroll
        for (int ni = 0; ni < 4; ++ni) O[mi][ni] = (v4f){0.f, 0.f, 0.f, 0.f};

    for (int it = 0; it < 32; ++it) {
        int c0 = colb + it * 64;
        __syncthreads();  // prev iter MFMA2 done before restaging
        for (int idx = tid; idx < 1024; idx += 256) {
            int r = idx >> 4, c8 = (idx & 15) << 3;
            *(uint4*)&ZC[r][c8] = *(const uint4*)(Zb + (c0 + r) * HID + c8);
        }
        for (int idx = tid; idx < 1024; idx += 256) {
            int hh = idx >> 3, c8 = (idx & 7) << 3;
            *(uint4*)&ZCT[hh][c8] = *(const uint4*)(ZbT + hh * NROWS + c0 + c8);
        }
        __syncthreads();
        // MFMA1: S[r][c] = sum_h ZR[r][h] * ZC[c][h]  (gemm_bt form)
        v4f S[2][2];
#pragma unroll
        for (int mi = 0; mi < 2; ++mi)
#pragma unroll
            for (int ni = 0; ni < 2; ++ni) S[mi][ni] = (v4f){0.f, 0.f, 0.f, 0.f};
#pragma unroll
        for (int ks = 0; ks < 4; ++ks) {
            v8s a0 = *(const v8s*)&ZR[wr * 32 + lm][ks * 32 + lq * 8];
            v8s a1 = *(const v8s*)&ZR[wr * 32 + 16 + lm][ks * 32 + lq * 8];
            v8s b0 = *(const v8s*)&ZC[wc * 32 + lm][ks * 32 + lq * 8];
            v8s b1 = *(const v8s*)&ZC[wc * 32 + 16 + lm][ks * 32 + lq * 8];
            S[0][0] = __builtin_amdgcn_mfma_f32_16x16x32_bf16(a0, b0, S[0][0], 0, 0, 0);
            S[0][1] = __builtin_amdgcn_mfma_f32_16x16x32_bf16(a0, b1, S[0][1], 0, 0, 0);
            S[1][0] = __builtin_amdgcn_mfma_f32_16x16x32_bf16(a1, b0, S[1][0], 0, 0, 0);
            S[1][1] = __builtin_amdgcn_mfma_f32_16x16x32_bf16(a1, b1, S[1][1], 0, 0, 0);
        }
        // relu + normalize; write fp32 A to global, bf16 A tile to LDS
#pragma unroll
        for (int mi = 0; mi < 2; ++mi)
#pragma unroll
            for (int ni = 0; ni < 2; ++ni)
#pragma unroll
                for (int j = 0; j < 4; ++j) {
                    float s = fmaxf(S[mi][ni][j], 0.f) * rsv[mi][j];
                    int rl = wr * 32 + mi * 16 + lq * 4 + j;
                    int cl = wc * 32 + ni * 16 + lm;
                    Ap[(row0 + rl) * NROWS + (c0 + cl)] = s;
                    Abf[rl][cl] = f2bf(s);
                }
        __syncthreads();
        // MFMA2: out[r][h] += sum_c Abf[r][c] * Z[c][h]; B-operand from ZCT[h][c]
#pragma unroll
        for (int ks = 0; ks < 2; ++ks) {
            v8s a0 = *(const v8s*)&Abf[wr * 32 + lm][ks * 32 + lq * 8];
            v8s a1 = *(const v8s*)&Abf[wr * 32 + 16 + lm][ks * 32 + lq * 8];
#pragma unroll
            for (int ni = 0; ni < 4; ++ni) {
                v8s b = *(const v8s*)&ZCT[wc * 64 + ni * 16 + lm][ks * 32 + lq * 8];
                O[0][ni] = __builtin_amdgcn_mfma_f32_16x16x32_bf16(a0, b, O[0][ni], 0, 0, 0);
                O[1][ni] = __builtin_amdgcn_mfma_f32_16x16x32_bf16(a1, b, O[1][ni], 0, 0, 0);
            }
        }
    }
#pragma unroll
    for (int mi = 0; mi < 2; ++mi)
#pragma unroll
        for (int ni = 0; ni < 4; ++ni)
#pragma unroll
            for (int j = 0; j < 4; ++j) {
                int r = row0 + wr * 32 + mi * 16 + lq * 4 + j;
                int hh = wc * 64 + ni * 16 + lm;
                atomicAdd(&outp[r * HID + hh], O[mi][ni][j]);
            }
}

extern "C" void kernel_launch(void* const* d_in, const int* in_sizes, int n_in,
                              void* d_out, int out_size, void* d_ws, size_t ws_size,
                              hipStream_t stream) {
    (void)in_sizes; (void)n_in; (void)out_size; (void)ws_size;
    const float* X = (const float*)d_in[0];
    const float* W = (const float*)d_in[1];
    float* outp = (float*)d_out;
    float* Ap = outp + (size_t)NROWS * HID;           // A follows out in d_out
    char* ws = (char*)d_ws;
    ushort* Zb = (ushort*)ws;                          // 2 MB
    ushort* ZbT = (ushort*)(ws + (size_t)NROWS * HID * 2);   // 2 MB
    float* rowsum = (float*)(ws + (size_t)NROWS * HID * 4);  // 32 KB

    hipMemsetAsync(outp, 0, (size_t)NROWS * HID * sizeof(float), stream);
    hipMemsetAsync(rowsum, 0, NROWS * sizeof(float), stream);
    k_z<<<dim3(NROWS / 16), dim3(256), 0, stream>>>(X, W, Zb, ZbT);
    k_rowsum<<<dim3(512), dim3(256), 0, stream>>>(Zb, rowsum);
    k_main<<<dim3(512), dim3(256), 0, stream>>>(Zb, ZbT, rowsum, outp, Ap);
}

// Round 3
// 367.718 us; speedup vs baseline: 1.1794x; 1.1794x over previous
//
#include <hip/hip_runtime.h>

// AdaptiveGraph on MI355X.
// K1: Z = X W^T via bf16 MFMA with hi/lo split (fp32-accurate); writes Zb [n][h] + ZbT [h][n] bf16.
// K2: rowsum[r] = sum_c relu(Z_r . Z_c). 128x128 block tiles, 64x64/wave, reg-cached ZR frags.
// K3: recompute S^T tiles (c-major C-layout -> float4 A-stores + b64 P-stores),
//     A = relu(S)*rsinv (fp32, nontemporal), out += P @ Z via second MFMA, atomicAdd.

#define NR 8192
#define KD 256
#define HD 128

typedef short v8s __attribute__((ext_vector_type(8)));
typedef float v4f __attribute__((ext_vector_type(4)));

static __device__ __forceinline__ ushort f2bf(float f) {
    union { float f; unsigned u; } c; c.f = f;
    unsigned u = c.u;
    u += 0x7fffu + ((u >> 16) & 1u);  // RNE; inputs finite
    return (ushort)(u >> 16);
}
static __device__ __forceinline__ float bf2f(ushort b) {
    union { unsigned u; float f; } c; c.u = ((unsigned)b) << 16; return c.f;
}
static __device__ __forceinline__ unsigned pk2(float a, float b) {
    union { float f; unsigned u; } x, y; x.f = a; y.f = b;
    unsigned ua = x.u + 0x7fffu + ((x.u >> 16) & 1u);
    unsigned ub = y.u + 0x7fffu + ((y.u >> 16) & 1u);
    return (ua >> 16) | (ub & 0xffff0000u);
}

// ---------------- K1: Z = X @ W^T (MFMA, hi/lo bf16 split) ----------------
// grid 256 blocks x 256 thr; block = 32 rows of X; wave owns 32 h-columns.
__global__ __launch_bounds__(256) void k_z(const float* __restrict__ X,
                                           const float* __restrict__ W,
                                           ushort* __restrict__ Zb,
                                           ushort* __restrict__ ZbT) {
    __shared__ ushort Xhi[32][264];  // +8 pad: stride 132 dwords == 4 mod 32 -> 2-way (free)
    __shared__ ushort Xlo[32][264];
    int tid = threadIdx.x, lane = tid & 63, wave = tid >> 6;
    int lm = lane & 15, lq = lane >> 4;
    int n0 = blockIdx.x * 32;
    int hbase = wave * 32;
    // W fragments cached in regs (hi/lo), reused for both n-tiles
    v8s Whi[2][8], Wlo[2][8];
#pragma unroll
    for (int hi = 0; hi < 2; ++hi) {
        const float* wp = W + (hbase + hi * 16 + lm) * KD + lq * 8;
#pragma unroll
        for (int ks = 0; ks < 8; ++ks) {
            float4 w0 = *(const float4*)(wp + ks * 32);
            float4 w1 = *(const float4*)(wp + ks * 32 + 4);
            float wv[8] = {w0.x, w0.y, w0.z, w0.w, w1.x, w1.y, w1.z, w1.w};
#pragma unroll
            for (int j = 0; j < 8; ++j) {
                ushort h = f2bf(wv[j]);
                Whi[hi][ks][j] = (short)h;
                Wlo[hi][ks][j] = (short)f2bf(wv[j] - bf2f(h));
            }
        }
    }
    // stage X tile 32x256 as hi/lo bf16
#pragma unroll
    for (int t = 0; t < 8; ++t) {
        int idx = tid + t * 256;
        int r = idx >> 6, c4 = (idx & 63) * 4;
        float4 x = *(const float4*)(X + (size_t)(n0 + r) * KD + c4);
        ushort h0 = f2bf(x.x), h1 = f2bf(x.y), h2 = f2bf(x.z), h3 = f2bf(x.w);
        unsigned a = ((unsigned)h0) | ((unsigned)h1 << 16);
        unsigned b = ((unsigned)h2) | ((unsigned)h3 << 16);
        unsigned c = ((unsigned)f2bf(x.x - bf2f(h0))) | ((unsigned)f2bf(x.y - bf2f(h1)) << 16);
        unsigned d = ((unsigned)f2bf(x.z - bf2f(h2))) | ((unsigned)f2bf(x.w - bf2f(h3)) << 16);
        *(uint2*)&Xhi[r][c4] = make_uint2(a, b);
        *(uint2*)&Xlo[r][c4] = make_uint2(c, d);
    }
    __syncthreads();
#pragma unroll
    for (int ni = 0; ni < 2; ++ni) {
        v8s Ah[8], Al[8];
#pragma unroll
        for (int ks = 0; ks < 8; ++ks) {
            Ah[ks] = *(const v8s*)&Xhi[ni * 16 + lm][ks * 32 + lq * 8];
            Al[ks] = *(const v8s*)&Xlo[ni * 16 + lm][ks * 32 + lq * 8];
        }
        v4f acc[2] = {{0.f, 0.f, 0.f, 0.f}, {0.f, 0.f, 0.f, 0.f}};
#pragma unroll
        for (int ks = 0; ks < 8; ++ks)
#pragma unroll
            for (int hi = 0; hi < 2; ++hi) {
                acc[hi] = __builtin_amdgcn_mfma_f32_16x16x32_bf16(Ah[ks], Whi[hi][ks], acc[hi], 0, 0, 0);
                acc[hi] = __builtin_amdgcn_mfma_f32_16x16x32_bf16(Ah[ks], Wlo[hi][ks], acc[hi], 0, 0, 0);
                acc[hi] = __builtin_amdgcn_mfma_f32_16x16x32_bf16(Al[ks], Whi[hi][ks], acc[hi], 0, 0, 0);
            }
#pragma unroll
        for (int hi = 0; hi < 2; ++hi) {
            int h = hbase + hi * 16 + lm;   // D: col=lm -> h, row=lq*4+j -> n
            int nb = n0 + ni * 16 + lq * 4;
            ushort b0 = f2bf(acc[hi][0]), b1 = f2bf(acc[hi][1]);
            ushort b2 = f2bf(acc[hi][2]), b3 = f2bf(acc[hi][3]);
            Zb[(size_t)(nb + 0) * HD + h] = b0;
            Zb[(size_t)(nb + 1) * HD + h] = b1;
            Zb[(size_t)(nb + 2) * HD + h] = b2;
            Zb[(size_t)(nb + 3) * HD + h] = b3;
            *(uint2*)&ZbT[(size_t)h * NR + nb] =
                make_uint2(((unsigned)b0) | ((unsigned)b1 << 16), ((unsigned)b2) | ((unsigned)b3 << 16));
        }
    }
}

// ---------------- K2: rowsum ----------------
// grid 512 = 64 rb x 8 cs; block tile 128r x (8 iters x 128c); wave = 64r x 64c.
__global__ __launch_bounds__(256) void k_rowsum(const ushort* __restrict__ Zb,
                                                float* __restrict__ rowsum) {
    __shared__ ushort ZR[128][136];
    __shared__ ushort ZC[128][136];
    int tid = threadIdx.x, lane = tid & 63, wave = tid >> 6;
    int lm = lane & 15, lq = lane >> 4;
    int rb = blockIdx.x >> 3, cs = blockIdx.x & 7;
    int row0 = rb * 128, cstart = cs * 1024;
#pragma unroll
    for (int t = 0; t < 8; ++t) {
        int idx = tid + t * 256;
        int r = idx >> 4, c8 = (idx & 15) * 8;
        *(uint4*)&ZR[r][c8] = *(const uint4*)(Zb + (size_t)(row0 + r) * HD + c8);
    }
    __syncthreads();
    int wr2 = wave >> 1, wc2 = wave & 1;
    v8s Bfr[4][4];  // reg-cached ZR frags (B-operand for S^T)
#pragma unroll
    for (int ri = 0; ri < 4; ++ri)
#pragma unroll
        for (int ks = 0; ks < 4; ++ks)
            Bfr[ri][ks] = *(const v8s*)&ZR[wr2 * 64 + ri * 16 + lm][ks * 32 + lq * 8];
    float rs[4] = {0.f, 0.f, 0.f, 0.f};
    for (int it = 0; it < 8; ++it) {
        int c0 = cstart + it * 128;
        __syncthreads();
#pragma unroll
        for (int t = 0; t < 8; ++t) {
            int idx = tid + t * 256;
            int r = idx >> 4, c8 = (idx & 15) * 8;
            *(uint4*)&ZC[r][c8] = *(const uint4*)(Zb + (size_t)(c0 + r) * HD + c8);
        }
        __syncthreads();
#pragma unroll
        for (int ci = 0; ci < 4; ++ci) {
            v8s Af[4];
#pragma unroll
            for (int ks = 0; ks < 4; ++ks)
                Af[ks] = *(const v8s*)&ZC[wc2 * 64 + ci * 16 + lm][ks * 32 + lq * 8];
            v4f acc[4] = {{0.f,0.f,0.f,0.f},{0.f,0.f,0.f,0.f},{0.f,0.f,0.f,0.f},{0.f,0.f,0.f,0.f}};
#pragma unroll
            for (int ks = 0; ks < 4; ++ks)
#pragma unroll
                for (int ri = 0; ri < 4; ++ri)
                    acc[ri] = __builtin_amdgcn_mfma_f32_16x16x32_bf16(Af[ks], Bfr[ri][ks], acc[ri], 0, 0, 0);
#pragma unroll
            for (int ri = 0; ri < 4; ++ri)
                rs[ri] += fmaxf(acc[ri][0], 0.f) + fmaxf(acc[ri][1], 0.f) +
                          fmaxf(acc[ri][2], 0.f) + fmaxf(acc[ri][3], 0.f);
        }
    }
#pragma unroll
    for (int ri = 0; ri < 4; ++ri) {
        float v = rs[ri];
        v += __shfl_xor(v, 16, 64);
        v += __shfl_xor(v, 32, 64);
        if (lq == 0) atomicAdd(&rowsum[row0 + wr2 * 64 + ri * 16 + lm], v);
    }
}

// ---------------- K3: A write + out accumulate ----------------
// grid 512 = 128 rb x 4 cs; block tile 64r x (32 iters x 64c); wave = 32r x 32c (S) / 32r x 64h (U).
__global__ __launch_bounds__(256) void k_main(const ushort* __restrict__ Zb,
                                              const ushort* __restrict__ ZbT,
                                              const float* __restrict__ rowsum,
                                              float* __restrict__ outp,
                                              float* __restrict__ Ap) {
    __shared__ ushort ZR[64][136];
    __shared__ ushort ZC[64][136];
    __shared__ ushort ZCT[128][72];  // Z tile [h][c] for U B-operand
    __shared__ ushort PT[64][72];    // normalized A tile bf16, [r][c]
    int tid = threadIdx.x, lane = tid & 63, wave = tid >> 6;
    int lm = lane & 15, lq = lane >> 4;
    int rb = blockIdx.x >> 2, cs = blockIdx.x & 3;
    int row0 = rb * 64, colb = cs * 2048;
#pragma unroll
    for (int t = 0; t < 4; ++t) {
        int idx = tid + t * 256;
        int r = idx >> 4, c8 = (idx & 15) * 8;
        *(uint4*)&ZR[r][c8] = *(const uint4*)(Zb + (size_t)(row0 + r) * HD + c8);
    }
    __syncthreads();
    int wr2 = wave >> 1, wc2 = wave & 1;
    v8s Bfr[2][4];  // reg-cached ZR frags
#pragma unroll
    for (int ri = 0; ri < 2; ++ri)
#pragma unroll
        for (int ks = 0; ks < 4; ++ks)
            Bfr[ri][ks] = *(const v8s*)&ZR[wr2 * 32 + ri * 16 + lm][ks * 32 + lq * 8];
    float rsv[2];
#pragma unroll
    for (int ri = 0; ri < 2; ++ri)
        rsv[ri] = 1.0f / (rowsum[row0 + wr2 * 32 + ri * 16 + lm] + 1e-6f);
    v4f U[2][4];
#pragma unroll
    for (int ri = 0; ri < 2; ++ri)
#pragma unroll
        for (int hi = 0; hi < 4; ++hi) U[ri][hi] = (v4f){0.f, 0.f, 0.f, 0.f};

    for (int it = 0; it < 32; ++it) {
        int c0 = colb + it * 64;
        __syncthreads();  // prev MFMA2 reads of ZCT/PT done
#pragma unroll
        for (int t = 0; t < 4; ++t) {
            int idx = tid + t * 256;
            int r = idx >> 4, c8 = (idx & 15) * 8;
            *(uint4*)&ZC[r][c8] = *(const uint4*)(Zb + (size_t)(c0 + r) * HD + c8);
        }
#pragma unroll
        for (int t = 0; t < 4; ++t) {
            int idx = tid + t * 256;
            int hh = idx >> 3, cc8 = (idx & 7) * 8;
            *(uint4*)&ZCT[hh][cc8] = *(const uint4*)(ZbT + (size_t)hh * NR + c0 + cc8);
        }
        __syncthreads();
        // S^T = (ZC as A) x (ZR as B): D[m=c][n=r] -> lane: r=lm, c=lq*4+reg (4 consecutive c!)
#pragma unroll
        for (int ci = 0; ci < 2; ++ci) {
            v8s Af[4];
#pragma unroll
            for (int ks = 0; ks < 4; ++ks)
                Af[ks] = *(const v8s*)&ZC[wc2 * 32 + ci * 16 + lm][ks * 32 + lq * 8];
            v4f S0 = {0.f, 0.f, 0.f, 0.f}, S1 = {0.f, 0.f, 0.f, 0.f};
#pragma unroll
            for (int ks = 0; ks < 4; ++ks) {
                S0 = __builtin_amdgcn_mfma_f32_16x16x32_bf16(Af[ks], Bfr[0][ks], S0, 0, 0, 0);
                S1 = __builtin_amdgcn_mfma_f32_16x16x32_bf16(Af[ks], Bfr[1][ks], S1, 0, 0, 0);
            }
            int cb = wc2 * 32 + ci * 16 + lq * 4;
            {
                int r = wr2 * 32 + lm;
                v4f av;
                av[0] = fmaxf(S0[0], 0.f) * rsv[0]; av[1] = fmaxf(S0[1], 0.f) * rsv[0];
                av[2] = fmaxf(S0[2], 0.f) * rsv[0]; av[3] = fmaxf(S0[3], 0.f) * rsv[0];
                __builtin_nontemporal_store(av, (v4f*)(Ap + (size_t)(row0 + r) * NR + c0 + cb));
                *(uint2*)&PT[r][cb] = make_uint2(pk2(av[0], av[1]), pk2(av[2], av[3]));
            }
            {
                int r = wr2 * 32 + 16 + lm;
                v4f av;
                av[0] = fmaxf(S1[0], 0.f) * rsv[1]; av[1] = fmaxf(S1[1], 0.f) * rsv[1];
                av[2] = fmaxf(S1[2], 0.f) * rsv[1]; av[3] = fmaxf(S1[3], 0.f) * rsv[1];
                __builtin_nontemporal_store(av, (v4f*)(Ap + (size_t)(row0 + r) * NR + c0 + cb));
                *(uint2*)&PT[r][cb] = make_uint2(pk2(av[0], av[1]), pk2(av[2], av[3]));
            }
        }
        __syncthreads();
        // U[r][h] += P[r][c] * Z[c][h]; A = PT frag, B = ZCT frag
#pragma unroll
        for (int ks = 0; ks < 2; ++ks) {
            v8s P0 = *(const v8s*)&PT[wr2 * 32 + lm][ks * 32 + lq * 8];
            v8s P1 = *(const v8s*)&PT[wr2 * 32 + 16 + lm][ks * 32 + lq * 8];
#pragma unroll
            for (int hi = 0; hi < 4; ++hi) {
                v8s Bz = *(const v8s*)&ZCT[wc2 * 64 + hi * 16 + lm][ks * 32 + lq * 8];
                U[0][hi] = __builtin_amdgcn_mfma_f32_16x16x32_bf16(P0, Bz, U[0][hi], 0, 0, 0);
                U[1][hi] = __builtin_amdgcn_mfma_f32_16x16x32_bf16(P1, Bz, U[1][hi], 0, 0, 0);
            }
        }
    }
#pragma unroll
    for (int ri = 0; ri < 2; ++ri)
#pragma unroll
        for (int hi = 0; hi < 4; ++hi)
#pragma unroll
            for (int j = 0; j < 4; ++j)
                atomicAdd(&outp[(size_t)(row0 + wr2 * 32 + ri * 16 + lq * 4 + j) * HD +
                                wc2 * 64 + hi * 16 + lm],
                          U[ri][hi][j]);
}

extern "C" void kernel_launch(void* const* d_in, const int* in_sizes, int n_in,
                              void* d_out, int out_size, void* d_ws, size_t ws_size,
                              hipStream_t stream) {
    (void)in_sizes; (void)n_in; (void)out_size; (void)ws_size;
    const float* X = (const float*)d_in[0];
    const float* W = (const float*)d_in[1];
    float* outp = (float*)d_out;
    float* Ap = outp + (size_t)NR * HD;  // A follows out in d_out
    char* ws = (char*)d_ws;
    ushort* Zb = (ushort*)ws;                                 // 2 MB
    ushort* ZbT = (ushort*)(ws + (size_t)NR * HD * 2);        // 2 MB
    float* rowsum = (float*)(ws + (size_t)NR * HD * 4);       // 32 KB

    (void)hipMemsetAsync(outp, 0, (size_t)NR * HD * sizeof(float), stream);
    (void)hipMemsetAsync(rowsum, 0, NR * sizeof(float), stream);
    k_z<<<dim3(NR / 32), dim3(256), 0, stream>>>(X, W, Zb, ZbT);
    k_rowsum<<<dim3(512), dim3(256), 0, stream>>>(Zb, rowsum);
    k_main<<<dim3(512), dim3(256), 0, stream>>>(Zb, ZbT, rowsum, outp, Ap);
}